// Round 22
// baseline (86.528 us; speedup 1.0000x reference)
//
#include <hip/hip_runtime.h>
#include <hip/hip_bf16.h>

#define N_ 32
#define C_ 128
#define H_ 56
#define W_ 56
#define K_ 256
#define HW_ (H_*W_)
#define HP_ 58   // padded spatial dim
#define PL_ 234  // LDS plane stride in 16B units (bank offsets {0,8,16,24})

typedef __attribute__((ext_vector_type(8))) __bf16 bf16x8;
typedef __attribute__((ext_vector_type(8))) unsigned short ushort8;
typedef __attribute__((ext_vector_type(4))) float f32x4;

typedef __attribute__((address_space(1))) const unsigned int g1_u32;
typedef __attribute__((address_space(3))) unsigned int l3_u32;

__device__ __forceinline__ void dma16(const void* g, void* l) {
    __builtin_amdgcn_global_load_lds((g1_u32*)g, (l3_u32*)l, 16, 0, 0);
}

__device__ __forceinline__ unsigned short f2bf(float f) {
    unsigned int u = __builtin_bit_cast(unsigned int, f);
    u += 0x7FFFu + ((u >> 16) & 1u);   // round-to-nearest-even
    return (unsigned short)(u >> 16);
}

// ---------------- weight repack: OIHW fp32 -> fragment-major bf16 ----------
// wp2[((tap*16 + kg)*4 + cc)*64 + lane][j]: k = kg*16+(lane&15), c = cc*32+(lane>>4)*8+j
__global__ void repack_w2_kernel(const float* __restrict__ w,
                                 unsigned short* __restrict__ wp2) {
    int o = blockIdx.x * 256 + threadIdx.x;
    if (o >= 9 * 16 * 4 * 64 * 8) return;
    int j   = o & 7;
    int l   = (o >> 3) & 63;
    int cc  = (o >> 9) & 3;
    int kg  = (o >> 11) & 15;
    int tap = o >> 15;
    int k = kg * 16 + (l & 15);
    int c = cc * 32 + (l >> 4) * 8 + j;
    wp2[o] = f2bf(w[(k * C_ + c) * 9 + tap]);
}

// ---------------- x prepack: NCHW fp32 -> padded NHWC bf16 -----------------
__global__ void pack_x_kernel(const float* __restrict__ x,
                              unsigned short* __restrict__ xp) {
    __shared__ unsigned short Lt[128 * 57];
    const int t  = threadIdx.x;               // 256
    const int b  = blockIdx.x;                // n*58 + hp
    const int n  = b / HP_;
    const int hp = b - n * HP_;
    unsigned short* orow = xp + ((size_t)(n * HP_ + hp) * HP_) * 128;

    ushort8 z = {0, 0, 0, 0, 0, 0, 0, 0};
    if (hp == 0 || hp == HP_ - 1) {
        for (int u = t; u < 928; u += 256)
            *(ushort8*)(orow + u * 8) = z;
        return;
    }
    const int h = hp - 1;
    const float* src = x + ((size_t)n * C_ * HW_ + h * W_);
    #pragma unroll
    for (int k = 0; k < 28; ++k) {
        int idx = k * 256 + t;
        int c = idx / 56, w2 = idx - 56 * c;
        Lt[c * 57 + w2] = f2bf(src[c * HW_ + w2]);
    }
    __syncthreads();
    for (int u = t; u < 928; u += 256) {
        int wp = u >> 4, c8 = u & 15;
        ushort8 v = z;
        if (wp >= 1 && wp <= 56) {
            #pragma unroll
            for (int j = 0; j < 8; ++j)
                v[j] = Lt[(c8 * 8 + j) * 57 + (wp - 1)];
        }
        *(ushort8*)(orow + u * 8) = v;
    }
}

// ---------------- main conv: champion structure, B-reuse = 4 ---------------
// Block: 256 kout x 64 flat px (one image; 3136 = 49*64, no crossing),
// 4 waves M-split: wave = 64 kout x 64 px (mi=4, ni=4, acc=64). Window =
// 4 padded rows x 58 cols = 232 cols (identical to champion; last block
// ends exactly at xp end, no clamp). LDS ring-3 x 16KB = 48KB -> 3 blocks/CU
// = 12 waves/CU at launch_bounds(256,3). Per tap: 4 B ds_reads (reuse 4) +
// 4 A parity-prefetch loads + 16 MFMA. Counted vmcnt(8)/(4), stage-after,
// setprio. Port ~24us < matrix 28.5us: matrix-bound at champion occupancy.
__launch_bounds__(256, 3)
__global__ void conv_mfma20_kernel(const unsigned short* __restrict__ xp,
                                   const unsigned short* __restrict__ wp2,
                                   const float* __restrict__ bias,
                                   float* __restrict__ out) {
    __shared__ __align__(16) unsigned char Xt[3][16384];

    const int t    = threadIdx.x;
    const int lane = t & 63;
    const int wid  = t >> 6;     // 0..3 : 64-kout group
    const int lp   = lane & 15;  // px sub-index
    const int lk   = lane >> 4;  // k-subgroup (8 ch each)

    // bijective XCD swizzle (1568 % 8 == 0): 196 contiguous blocks per XCD
    const int b    = blockIdx.x;
    const int orig = (b & 7) * 196 + (b >> 3);
    const int n    = orig / 49;
    const int kt   = orig - n * 49;
    const int px0  = kt * 64;            // flat px in image n
    const int h0   = px0 / W_;           // first output row
    const size_t wbase = ((size_t)n * HP_ + h0) * HP_;  // window element base

    // per-ni B column bases (tap adds r*58 + s)
    int bunit[4];
    #pragma unroll
    for (int ni = 0; ni < 4; ++ni) {
        int px = px0 + ni * 16 + lp;
        int h  = px / W_;
        int w2 = px - W_ * h;
        bunit[ni] = (lk * PL_ + (h - h0) * HP_ + w2) * 16;
    }

    // staging: 4 DMAs/thread; linear dest unit u realizes [slot][col] via
    // source (slot = u/PL_, col = u%PL_); pad slots clamp (never read).
    const unsigned short* gsrc[4];
    #pragma unroll
    for (int i = 0; i < 4; ++i) {
        int u    = i * 256 + t;
        int slot = u / PL_;
        int col  = u - PL_ * slot;
        bool ok  = (slot < 4) && (col < 232);
        int ssl  = ok ? slot : 0;
        int scol = ok ? col : 0;
        gsrc[i]  = xp + (wbase + scol) * 128 + ssl * 8;
    }

    f32x4 acc[4][4];
    #pragma unroll
    for (int mi = 0; mi < 4; ++mi)
        #pragma unroll
        for (int ni = 0; ni < 4; ++ni)
            acc[mi][ni] = (f32x4){0.f, 0.f, 0.f, 0.f};

    const ushort8* W8 = (const ushort8*)wp2;
    bf16x8 areg[2][4];   // [parity][mi]; wave owns kg = wid*4 + mi

#define STAGE(CH, BUF)                                                     \
    _Pragma("unroll")                                                      \
    for (int i = 0; i < 4; ++i)                                            \
        dma16(gsrc[i] + (CH) * 32, Xt[BUF] + (i * 256 + t) * 16);

#define LOAD_A(TAP, CC, PAR)                                               \
    _Pragma("unroll")                                                      \
    for (int mi = 0; mi < 4; ++mi)                                         \
        areg[PAR][mi] = __builtin_bit_cast(bf16x8,                         \
            W8[(TAP) * 4096 + ((wid * 4 + mi) * 4 + (CC)) * 64 + lane]);

    // prologue: A(0) first (earliest L2 issue), then DMA chunks 0,1
    LOAD_A(0, 0, 0)
    STAGE(0, 0)
    STAGE(1, 1)
    asm volatile("s_waitcnt vmcnt(4)" ::: "memory");   // A(0)+buf0 landed
    __builtin_amdgcn_s_barrier();

    #pragma unroll
    for (int cc = 0; cc < 4; ++cc) {
        const int cur = cc % 3;

        #pragma unroll
        for (int tap = 0; tap < 9; ++tap) {
            const int g = cc * 9 + tap;     // global tap index (compile-time)
            const int p = g & 1;

            const int r    = tap / 3;
            const int s    = tap - 3 * r;
            const int toff = (r * HP_ + s) * 16;

            bf16x8 bfr[4];
            #pragma unroll
            for (int ni = 0; ni < 4; ++ni)
                bfr[ni] = __builtin_bit_cast(bf16x8,
                    *(const ushort8*)(Xt[cur] + bunit[ni] + toff));

            // prefetch A for global tap g+1 (crosses chunk boundary freely)
            if (g + 1 < 36) {
                const int nc = (g + 1) / 9;
                const int nt = (g + 1) - nc * 9;
                LOAD_A(nt, nc, p ^ 1)
            }

            __builtin_amdgcn_s_setprio(1);
            #pragma unroll
            for (int ni = 0; ni < 4; ++ni)
                #pragma unroll
                for (int mi = 0; mi < 4; ++mi)
                    acc[mi][ni] = __builtin_amdgcn_mfma_f32_16x16x32_bf16(
                        areg[p][mi], bfr[ni], acc[mi][ni], 0, 0, 0);
            __builtin_amdgcn_s_setprio(0);
        }

        if (cc < 2) { STAGE(cc + 2, (cc + 2) % 3) }    // newest vmem ops

        if (cc < 3) {
            // keep stage(cc+2) [if any] + newest A quad in flight
            if (cc < 2) asm volatile("s_waitcnt vmcnt(8)" ::: "memory");
            else        asm volatile("s_waitcnt vmcnt(4)" ::: "memory");
            __builtin_amdgcn_s_barrier();
        }
    }
#undef STAGE
#undef LOAD_A

    // epilogue: bias + fp32 store (block lies in one image; coalesced on lp)
    #pragma unroll
    for (int mi = 0; mi < 4; ++mi) {
        #pragma unroll
        for (int j = 0; j < 4; ++j) {
            int kout = wid * 64 + mi * 16 + lk * 4 + j;
            float bv = bias[kout];
            float* op = out + ((size_t)(n * K_ + kout) * HW_) + px0;
            #pragma unroll
            for (int ni = 0; ni < 4; ++ni)
                op[ni * 16 + lp] = acc[mi][ni][j] + bv;
        }
    }
}

// ---------------- fallback (reg-staged fp32 path, no workspace xp) ---------
__launch_bounds__(256, 2)
__global__ void conv_mfma3_kernel(const float* __restrict__ x,
                                  const unsigned short* __restrict__ wp2,
                                  const float* __restrict__ bias,
                                  float* __restrict__ out) {
    __shared__ unsigned short Xt[2][232 * 40];
    const int t    = threadIdx.x;
    const int lane = t & 63;
    const int wid  = t >> 6;
    const int b    = blockIdx.x;
    const int orig = (b & 7) * 112 + (b >> 3);
    const int n    = orig / 28;
    const int rp   = orig - n * 28;
    const int h0   = rp * 2;
    const int lp = lane & 15;
    const int lk = lane >> 4;
    int bofs[7];
    #pragma unroll
    for (int ni = 0; ni < 7; ++ni) {
        int p  = ni * 16 + lp;
        int hr = (p >= 56) ? 1 : 0;
        int pw = p - hr * 56;
        bofs[ni] = (hr * 58 + pw) * 40 + lk * 8;
    }
    bool  ok[4], v928[4];
    const float* xq[4];
    int   ldsw[4];
    #pragma unroll
    for (int i = 0; i < 4; ++i) {
        int it = i * 256 + t;
        v928[i] = (it < 928);
        int itc  = v928[i] ? it : 0;
        int csub = (itc >= 232) + (itc >= 464) + (itc >= 696);
        int col  = itc - 232 * csub;
        int hh   = col / 58;
        int ww   = col - 58 * hh;
        int hin  = h0 + hh - 1;
        int win  = ww - 1;
        ok[i]   = v928[i] && (unsigned)hin < 56u && (unsigned)win < 56u;
        xq[i]   = x + (((n * C_ + csub * 8) * H_ + hin) * W_ + win);
        ldsw[i] = col * 40 + csub * 8;
    }
    float xv[4][8];
#define STAGE_LOAD(CH)                                                 \
    _Pragma("unroll")                                                  \
    for (int i = 0; i < 4; ++i)                                        \
        _Pragma("unroll")                                              \
        for (int j = 0; j < 8; ++j)                                    \
            xv[i][j] = ok[i] ? xq[i][((CH) * 32 + j) * HW_] : 0.f;
#define STAGE_WRITE(BUF)                                               \
    _Pragma("unroll")                                                  \
    for (int i = 0; i < 4; ++i)                                        \
        if (v928[i]) {                                                 \
            ushort8 v;                                                 \
            _Pragma("unroll")                                          \
            for (int j = 0; j < 8; ++j) v[j] = f2bf(xv[i][j]);         \
            *(ushort8*)(&Xt[BUF][ldsw[i]]) = v;                        \
        }
    f32x4 acc[4][7];
    #pragma unroll
    for (int mi = 0; mi < 4; ++mi)
        #pragma unroll
        for (int ni = 0; ni < 7; ++ni)
            acc[mi][ni] = (f32x4){0.f, 0.f, 0.f, 0.f};
    STAGE_LOAD(0)
    STAGE_WRITE(0)
    __syncthreads();
    const ushort8* W8 = (const ushort8*)wp2;
    for (int cc = 0; cc < 4; ++cc) {
        const int cur = cc & 1;
        if (cc < 3) { STAGE_LOAD(cc + 1) }
        const int tb = wid * 1024 + cc * 64 + lane;
        #pragma unroll
        for (int tap = 0; tap < 9; ++tap) {
            const int r    = tap / 3;
            const int s    = tap - 3 * r;
            const int toff = (r * 58 + s) * 40;
            bf16x8 a[4];
            #pragma unroll
            for (int mi = 0; mi < 4; ++mi)
                a[mi] = __builtin_bit_cast(bf16x8, W8[tap * 4096 + tb + mi * 256]);
            bf16x8 bfr[7];
            #pragma unroll
            for (int ni = 0; ni < 7; ++ni)
                bfr[ni] = __builtin_bit_cast(bf16x8,
                    *(const ushort8*)(&Xt[cur][bofs[ni] + toff]));
            #pragma unroll
            for (int ni = 0; ni < 7; ++ni)
                #pragma unroll
                for (int mi = 0; mi < 4; ++mi)
                    acc[mi][ni] = __builtin_amdgcn_mfma_f32_16x16x32_bf16(
                        a[mi], bfr[ni], acc[mi][ni], 0, 0, 0);
        }
        if (cc < 3) {
            STAGE_WRITE(cur ^ 1)
            __syncthreads();
        }
    }
    #pragma unroll
    for (int mi = 0; mi < 4; ++mi) {
        #pragma unroll
        for (int j = 0; j < 4; ++j) {
            int kout = wid * 64 + mi * 16 + lk * 4 + j;
            float bv = bias[kout];
            float* op = out + ((n * K_ + kout) * H_ + h0) * W_;
            #pragma unroll
            for (int ni = 0; ni < 7; ++ni) {
                int p  = ni * 16 + lp;
                int hr = (p >= 56) ? 1 : 0;
                int pw = p - hr * 56;
                op[hr * W_ + pw] = acc[mi][ni][j] + bv;
            }
        }
    }
#undef STAGE_LOAD
#undef STAGE_WRITE
}

__global__ void conv_naive_kernel(const float* __restrict__ x,
                                  const float* __restrict__ w,
                                  const float* __restrict__ b,
                                  float* __restrict__ out) {
    int idx = blockIdx.x * 256 + threadIdx.x;
    if (idx >= N_ * K_ * HW_) return;
    int pw = idx % 56; int tmp = idx / 56;
    int h  = tmp % 56; tmp /= 56;
    int k  = tmp % 256; int n = tmp / 256;
    float acc = b[k];
    for (int c = 0; c < C_; ++c)
        for (int r = 0; r < 3; ++r) {
            int hin = h + r - 1;
            if ((unsigned)hin >= 56u) continue;
            for (int s = 0; s < 3; ++s) {
                int win = pw + s - 1;
                if ((unsigned)win >= 56u) continue;
                acc += x[((n * C_ + c) * H_ + hin) * W_ + win] * w[(k * C_ + c) * 9 + r * 3 + s];
            }
        }
    out[idx] = acc;
}

extern "C" void kernel_launch(void* const* d_in, const int* in_sizes, int n_in,
                              void* d_out, int out_size, void* d_ws, size_t ws_size,
                              hipStream_t stream) {
    const float* x = (const float*)d_in[0];
    const float* w = (const float*)d_in[1];
    const float* b = (const float*)d_in[2];
    float* out = (float*)d_out;

    const size_t xp_bytes = (size_t)N_ * HP_ * HP_ * C_ * 2;              // 27,557,888
    const size_t wp_bytes = (size_t)9 * 16 * 4 * 64 * 8 * 2;              // 589,824

    if (ws_size >= xp_bytes + wp_bytes) {
        unsigned short* xpad = (unsigned short*)d_ws;
        unsigned short* wp2  = (unsigned short*)((char*)d_ws + xp_bytes);
        pack_x_kernel<<<N_ * HP_, 256, 0, stream>>>(x, xpad);
        repack_w2_kernel<<<(9 * 16 * 4 * 64 * 8 + 255) / 256, 256, 0, stream>>>(w, wp2);
        conv_mfma20_kernel<<<1568, 256, 0, stream>>>(xpad, wp2, b, out);
    } else if (ws_size >= wp_bytes) {
        unsigned short* wp2 = (unsigned short*)d_ws;
        repack_w2_kernel<<<(9 * 16 * 4 * 64 * 8 + 255) / 256, 256, 0, stream>>>(w, wp2);
        conv_mfma3_kernel<<<896, 256, 0, stream>>>(x, wp2, b, out);
    } else {
        conv_naive_kernel<<<(N_ * K_ * HW_ + 255) / 256, 256, 0, stream>>>(x, w, b, out);
    }
}

// Round 23
// 76.733 us; speedup vs baseline: 1.1276x; 1.1276x over previous
//
#include <hip/hip_runtime.h>
#include <hip/hip_bf16.h>

#define N_ 32
#define C_ 128
#define H_ 56
#define W_ 56
#define K_ 256
#define HW_ (H_*W_)
#define HP_ 58   // padded spatial dim
#define PL_ 234  // LDS plane stride in 16B units

typedef __attribute__((ext_vector_type(8))) __bf16 bf16x8;
typedef __attribute__((ext_vector_type(8))) unsigned short ushort8;
typedef __attribute__((ext_vector_type(4))) float f32x4;

typedef __attribute__((address_space(1))) const unsigned int g1_u32;
typedef __attribute__((address_space(3))) unsigned int l3_u32;

__device__ __forceinline__ void dma16(const void* g, void* l) {
    __builtin_amdgcn_global_load_lds((g1_u32*)g, (l3_u32*)l, 16, 0, 0);
}

__device__ __forceinline__ unsigned short f2bf(float f) {
    unsigned int u = __builtin_bit_cast(unsigned int, f);
    u += 0x7FFFu + ((u >> 16) & 1u);   // round-to-nearest-even
    return (unsigned short)(u >> 16);
}

// ---------------- weight repack: OIHW fp32 -> fragment-major bf16 ----------
// wp2[((tap*16 + kg)*4 + cc)*64 + lane][j]: k = kg*16+(lane&15), c = cc*32+(lane>>4)*8+j
__global__ void repack_w2_kernel(const float* __restrict__ w,
                                 unsigned short* __restrict__ wp2) {
    int o = blockIdx.x * 256 + threadIdx.x;
    if (o >= 9 * 16 * 4 * 64 * 8) return;
    int j   = o & 7;
    int l   = (o >> 3) & 63;
    int cc  = (o >> 9) & 3;
    int kg  = (o >> 11) & 15;
    int tap = o >> 15;
    int k = kg * 16 + (l & 15);
    int c = cc * 32 + (l >> 4) * 8 + j;
    wp2[o] = f2bf(w[(k * C_ + c) * 9 + tap]);
}

// ---------------- x prepack: NCHW fp32 -> padded NHWC bf16 -----------------
__global__ void pack_x_kernel(const float* __restrict__ x,
                              unsigned short* __restrict__ xp) {
    __shared__ unsigned short Lt[128 * 57];
    const int t  = threadIdx.x;               // 256
    const int b  = blockIdx.x;                // n*58 + hp
    const int n  = b / HP_;
    const int hp = b - n * HP_;
    unsigned short* orow = xp + ((size_t)(n * HP_ + hp) * HP_) * 128;

    ushort8 z = {0, 0, 0, 0, 0, 0, 0, 0};
    if (hp == 0 || hp == HP_ - 1) {
        for (int u = t; u < 928; u += 256)
            *(ushort8*)(orow + u * 8) = z;
        return;
    }
    const int h = hp - 1;
    const float* src = x + ((size_t)n * C_ * HW_ + h * W_);
    #pragma unroll
    for (int k = 0; k < 28; ++k) {
        int idx = k * 256 + t;
        int c = idx / 56, w2 = idx - 56 * c;
        Lt[c * 57 + w2] = f2bf(src[c * HW_ + w2]);
    }
    __syncthreads();
    for (int u = t; u < 928; u += 256) {
        int wp = u >> 4, c8 = u & 15;
        ushort8 v = z;
        if (wp >= 1 && wp <= 56) {
            #pragma unroll
            for (int j = 0; j < 8; ++j)
                v[j] = Lt[(c8 * 8 + j) * 57 + (wp - 1)];
        }
        *(ushort8*)(orow + u * 8) = v;
    }
}

// ---------------- main conv: champion (R15/R21) — mi=2, 12 waves/CU --------
// Block: 128 kout x 112 px (2 rows), 4 waves, each wave 32 kout x 112 px
// (mi=2, ni=7, acc=56). Grid 1792. 3-buffer B ring (48 KB) -> 3 blocks/CU
// at launch_bounds(256,3) => 12 waves/CU (3/SIMD). Per chunk: 63 B ds_reads
// + per-tap A-parity-prefetch from L2 + 126 MFMA; counted vmcnt, 3 barriers.
// Measured: main 58.3us, MfmaUtil 42%, occupancy 25.6% (reproduced twice).
__launch_bounds__(256, 3)
__global__ void conv_mfma14_kernel(const unsigned short* __restrict__ xp,
                                   const unsigned short* __restrict__ wp2,
                                   const float* __restrict__ bias,
                                   float* __restrict__ out) {
    __shared__ __align__(16) unsigned char Xt[3][16384];

    const int t    = threadIdx.x;
    const int lane = t & 63;
    const int wid  = t >> 6;

    // bijective XCD swizzle (1792 % 8 == 0): 224 contiguous blocks per XCD
    const int b    = blockIdx.x;
    const int orig = (b & 7) * 224 + (b >> 3);
    const int kb   = orig & 1;          // 128-kout half
    const int cell = orig >> 1;         // consecutive origs share x-window
    const int n    = cell / 28;
    const int rp   = cell - n * 28;
    const int h0   = rp * 2;

    const int lp = lane & 15;
    const int lk = lane >> 4;

    // B-fragment byte offsets (tap adds (r*58+s)*16)
    int bunit[7];
    #pragma unroll
    for (int ni = 0; ni < 7; ++ni) {
        int p  = ni * 16 + lp;
        int hr = (p >= 56) ? 1 : 0;
        int pw = p - hr * 56;
        bunit[ni] = (lk * PL_ + hr * HP_ + pw) * 16;
    }

    // staging geometry: slot u = i*256+t -> (csub,col) = (u/PL_, u%PL_);
    // invalid slots clamp source to xp base (garbage lands in pad units).
    const unsigned short* gsrc[4];
    #pragma unroll
    for (int i = 0; i < 4; ++i) {
        int u    = i * 256 + t;
        int csub = u / PL_;
        int col  = u - PL_ * csub;
        bool ok  = (csub < 4) && (col < 232);
        int csc  = ok ? csub : 0;
        int colc = ok ? col : 0;
        int hh   = colc / HP_;
        int ww   = colc - HP_ * hh;
        gsrc[i]  = ok ? xp + (((size_t)(n * HP_ + h0 + hh) * HP_ + ww) * 128 + csc * 8)
                      : xp;
    }

    f32x4 acc[2][7];
    #pragma unroll
    for (int mi = 0; mi < 2; ++mi)
        #pragma unroll
        for (int ni = 0; ni < 7; ++ni)
            acc[mi][ni] = (f32x4){0.f, 0.f, 0.f, 0.f};

    const ushort8* W8 = (const ushort8*)wp2;
    const int kgbase = kb * 8 + wid * 2;   // wave owns kout [kgbase*16, +32)
    bf16x8 areg[2][2];                     // [parity][mi]

#define STAGE(CH, BUF)                                                     \
    _Pragma("unroll")                                                      \
    for (int i = 0; i < 4; ++i)                                            \
        dma16(gsrc[i] + (CH) * 32, Xt[BUF] + i * 4096 + wid * 1024);

#define LOAD_A(TAP, CC, PAR)                                               \
    _Pragma("unroll")                                                      \
    for (int mi = 0; mi < 2; ++mi)                                         \
        areg[PAR][mi] = __builtin_bit_cast(bf16x8,                         \
            W8[(TAP) * 4096 + ((kgbase + mi) * 4 + (CC)) * 64 + lane]);

    // prologue: A(0) first (earliest L2 issue), then DMA chunks 0,1
    LOAD_A(0, 0, 0)
    STAGE(0, 0)
    STAGE(1, 1)
    asm volatile("s_waitcnt vmcnt(4)" ::: "memory");   // A(0)+buf0 landed
    __builtin_amdgcn_s_barrier();

    #pragma unroll
    for (int cc = 0; cc < 4; ++cc) {
        const int cur = cc % 3;

        #pragma unroll
        for (int tap = 0; tap < 9; ++tap) {
            const int g = cc * 9 + tap;     // global tap index (compile-time)
            const int p = g & 1;

            const int r    = tap / 3;
            const int s    = tap - 3 * r;
            const int toff = (r * HP_ + s) * 16;

            bf16x8 bfr[7];
            #pragma unroll
            for (int ni = 0; ni < 7; ++ni)
                bfr[ni] = __builtin_bit_cast(bf16x8,
                    *(const ushort8*)(Xt[cur] + bunit[ni] + toff));

            // prefetch A for global tap g+1 (crosses chunk boundary freely)
            if (g + 1 < 36) {
                const int nc = (g + 1) / 9;
                const int nt = (g + 1) - nc * 9;
                LOAD_A(nt, nc, p ^ 1)
            }

            __builtin_amdgcn_s_setprio(1);
            #pragma unroll
            for (int ni = 0; ni < 7; ++ni)
                #pragma unroll
                for (int mi = 0; mi < 2; ++mi)
                    acc[mi][ni] = __builtin_amdgcn_mfma_f32_16x16x32_bf16(
                        areg[p][mi], bfr[ni], acc[mi][ni], 0, 0, 0);
            __builtin_amdgcn_s_setprio(0);
        }

        if (cc < 2) { STAGE(cc + 2, (cc + 2) % 3) }    // newest vmem ops

        if (cc < 3) {
            // keep stage(cc+2) [if any] + A-prefetch(2) in flight
            if (cc < 2) asm volatile("s_waitcnt vmcnt(6)" ::: "memory");
            else        asm volatile("s_waitcnt vmcnt(2)" ::: "memory");
            __builtin_amdgcn_s_barrier();
        }
    }
#undef STAGE
#undef LOAD_A

    // epilogue: bias + fp32 store
    #pragma unroll
    for (int mi = 0; mi < 2; ++mi) {
        #pragma unroll
        for (int j = 0; j < 4; ++j) {
            int kout = kb * 128 + wid * 32 + mi * 16 + lk * 4 + j;
            float bv = bias[kout];
            float* op = out + ((n * K_ + kout) * H_ + h0) * W_;
            #pragma unroll
            for (int ni = 0; ni < 7; ++ni) {
                int p  = ni * 16 + lp;
                int hr = (p >= 56) ? 1 : 0;
                int pw = p - hr * 56;
                op[hr * W_ + pw] = acc[mi][ni][j] + bv;
            }
        }
    }
}

// ---------------- fallback (reg-staged fp32 path, no workspace xp) ---------
__launch_bounds__(256, 2)
__global__ void conv_mfma3_kernel(const float* __restrict__ x,
                                  const unsigned short* __restrict__ wp2,
                                  const float* __restrict__ bias,
                                  float* __restrict__ out) {
    __shared__ unsigned short Xt[2][232 * 40];
    const int t    = threadIdx.x;
    const int lane = t & 63;
    const int wid  = t >> 6;
    const int b    = blockIdx.x;
    const int orig = (b & 7) * 112 + (b >> 3);
    const int n    = orig / 28;
    const int rp   = orig - n * 28;
    const int h0   = rp * 2;
    const int lp = lane & 15;
    const int lk = lane >> 4;
    int bofs[7];
    #pragma unroll
    for (int ni = 0; ni < 7; ++ni) {
        int p  = ni * 16 + lp;
        int hr = (p >= 56) ? 1 : 0;
        int pw = p - hr * 56;
        bofs[ni] = (hr * 58 + pw) * 40 + lk * 8;
    }
    bool  ok[4], v928[4];
    const float* xq[4];
    int   ldsw[4];
    #pragma unroll
    for (int i = 0; i < 4; ++i) {
        int it = i * 256 + t;
        v928[i] = (it < 928);
        int itc  = v928[i] ? it : 0;
        int csub = (itc >= 232) + (itc >= 464) + (itc >= 696);
        int col  = itc - 232 * csub;
        int hh   = col / 58;
        int ww   = col - 58 * hh;
        int hin  = h0 + hh - 1;
        int win  = ww - 1;
        ok[i]   = v928[i] && (unsigned)hin < 56u && (unsigned)win < 56u;
        xq[i]   = x + (((n * C_ + csub * 8) * H_ + hin) * W_ + win);
        ldsw[i] = col * 40 + csub * 8;
    }
    float xv[4][8];
#define STAGE_LOAD(CH)                                                 \
    _Pragma("unroll")                                                  \
    for (int i = 0; i < 4; ++i)                                        \
        _Pragma("unroll")                                              \
        for (int j = 0; j < 8; ++j)                                    \
            xv[i][j] = ok[i] ? xq[i][((CH) * 32 + j) * HW_] : 0.f;
#define STAGE_WRITE(BUF)                                               \
    _Pragma("unroll")                                                  \
    for (int i = 0; i < 4; ++i)                                        \
        if (v928[i]) {                                                 \
            ushort8 v;                                                 \
            _Pragma("unroll")                                          \
            for (int j = 0; j < 8; ++j) v[j] = f2bf(xv[i][j]);         \
            *(ushort8*)(&Xt[BUF][ldsw[i]]) = v;                        \
        }
    f32x4 acc[4][7];
    #pragma unroll
    for (int mi = 0; mi < 4; ++mi)
        #pragma unroll
        for (int ni = 0; ni < 7; ++ni)
            acc[mi][ni] = (f32x4){0.f, 0.f, 0.f, 0.f};
    STAGE_LOAD(0)
    STAGE_WRITE(0)
    __syncthreads();
    const ushort8* W8 = (const ushort8*)wp2;
    for (int cc = 0; cc < 4; ++cc) {
        const int cur = cc & 1;
        if (cc < 3) { STAGE_LOAD(cc + 1) }
        const int tb = wid * 1024 + cc * 64 + lane;
        #pragma unroll
        for (int tap = 0; tap < 9; ++tap) {
            const int r    = tap / 3;
            const int s    = tap - 3 * r;
            const int toff = (r * 58 + s) * 40;
            bf16x8 a[4];
            #pragma unroll
            for (int mi = 0; mi < 4; ++mi)
                a[mi] = __builtin_bit_cast(bf16x8, W8[tap * 4096 + tb + mi * 256]);
            bf16x8 bfr[7];
            #pragma unroll
            for (int ni = 0; ni < 7; ++ni)
                bfr[ni] = __builtin_bit_cast(bf16x8,
                    *(const ushort8*)(&Xt[cur][bofs[ni] + toff]));
            #pragma unroll
            for (int ni = 0; ni < 7; ++ni)
                #pragma unroll
                for (int mi = 0; mi < 4; ++mi)
                    acc[mi][ni] = __builtin_amdgcn_mfma_f32_16x16x32_bf16(
                        a[mi], bfr[ni], acc[mi][ni], 0, 0, 0);
        }
        if (cc < 3) {
            STAGE_WRITE(cur ^ 1)
            __syncthreads();
        }
    }
    #pragma unroll
    for (int mi = 0; mi < 4; ++mi) {
        #pragma unroll
        for (int j = 0; j < 4; ++j) {
            int kout = wid * 64 + mi * 16 + lk * 4 + j;
            float bv = bias[kout];
            float* op = out + ((n * K_ + kout) * H_ + h0) * W_;
            #pragma unroll
            for (int ni = 0; ni < 7; ++ni) {
                int p  = ni * 16 + lp;
                int hr = (p >= 56) ? 1 : 0;
                int pw = p - hr * 56;
                op[hr * W_ + pw] = acc[mi][ni][j] + bv;
            }
        }
    }
#undef STAGE_LOAD
#undef STAGE_WRITE
}

__global__ void conv_naive_kernel(const float* __restrict__ x,
                                  const float* __restrict__ w,
                                  const float* __restrict__ b,
                                  float* __restrict__ out) {
    int idx = blockIdx.x * 256 + threadIdx.x;
    if (idx >= N_ * K_ * HW_) return;
    int pw = idx % 56; int tmp = idx / 56;
    int h  = tmp % 56; tmp /= 56;
    int k  = tmp % 256; int n = tmp / 256;
    float acc = b[k];
    for (int c = 0; c < C_; ++c)
        for (int r = 0; r < 3; ++r) {
            int hin = h + r - 1;
            if ((unsigned)hin >= 56u) continue;
            for (int s = 0; s < 3; ++s) {
                int win = pw + s - 1;
                if ((unsigned)win >= 56u) continue;
                acc += x[((n * C_ + c) * H_ + hin) * W_ + win] * w[(k * C_ + c) * 9 + r * 3 + s];
            }
        }
    out[idx] = acc;
}

extern "C" void kernel_launch(void* const* d_in, const int* in_sizes, int n_in,
                              void* d_out, int out_size, void* d_ws, size_t ws_size,
                              hipStream_t stream) {
    const float* x = (const float*)d_in[0];
    const float* w = (const float*)d_in[1];
    const float* b = (const float*)d_in[2];
    float* out = (float*)d_out;

    const size_t xp_bytes = (size_t)N_ * HP_ * HP_ * C_ * 2;              // 27,557,888
    const size_t wp_bytes = (size_t)9 * 16 * 4 * 64 * 8 * 2;              // 589,824

    if (ws_size >= xp_bytes + wp_bytes) {
        unsigned short* xpad = (unsigned short*)d_ws;
        unsigned short* wp2  = (unsigned short*)((char*)d_ws + xp_bytes);
        pack_x_kernel<<<N_ * HP_, 256, 0, stream>>>(x, xpad);
        repack_w2_kernel<<<(9 * 16 * 4 * 64 * 8 + 255) / 256, 256, 0, stream>>>(w, wp2);
        conv_mfma14_kernel<<<1792, 256, 0, stream>>>(xpad, wp2, b, out);
    } else if (ws_size >= wp_bytes) {
        unsigned short* wp2 = (unsigned short*)d_ws;
        repack_w2_kernel<<<(9 * 16 * 4 * 64 * 8 + 255) / 256, 256, 0, stream>>>(w, wp2);
        conv_mfma3_kernel<<<896, 256, 0, stream>>>(x, wp2, b, out);
    } else {
        conv_naive_kernel<<<(N_ * K_ * HW_ + 255) / 256, 256, 0, stream>>>(x, w, b, out);
    }
}